// Round 8
// baseline (1562.221 us; speedup 1.0000x reference)
//
#include <hip/hip_runtime.h>
#include <math.h>

// Problem constants
#define B_   128
#define I_   2048
#define F_   8
#define J_   16
#define D_   16
#define JD   256
#define IT   16
#define NIT  (I_/IT)       // 128
#define BT   16
#define NBG  (B_/BT)       // 8
#define GRID (NIT*NBG)     // 1024 == 4 blocks/CU * 256 CUs (co-residency math below)
#define SROW 257           // padded slds row stride
#define JSTR ((size_t)I_*D_*F_)   // f16 elems between consecutive j planes

typedef _Float16 f16;
typedef _Float16 f16x8 __attribute__((ext_vector_type(8)));
typedef _Float16 f16x4 __attribute__((ext_vector_type(4)));
typedef float    f32x4 __attribute__((ext_vector_type(4)));

#if defined(__has_builtin)
#  if __has_builtin(__builtin_amdgcn_permlane32_swap)
#    define HAVE_PLS32 1
#  endif
#endif

// 16-lane DPP sum — pure VALU
template <int CTRL>
__device__ __forceinline__ float dpp_add(float v) {
    int t = __builtin_amdgcn_update_dpp(0, __float_as_int(v), CTRL, 0xF, 0xF, true);
    return v + __int_as_float(t);
}
__device__ __forceinline__ float row_sum16(float v) {
    v = dpp_add<0x128>(v);
    v = dpp_add<0x124>(v);
    v = dpp_add<0x122>(v);
    v = dpp_add<0x121>(v);
    return v;
}

// quarter-sum folds for MFMA C-layout (proven in rounds 5-7)
__device__ __forceinline__ float fold16(float p) {
    return p + __int_as_float(__builtin_amdgcn_ds_swizzle(__float_as_int(p), 0x401F));
}
__device__ __forceinline__ float fold32(float p) {
#ifdef HAVE_PLS32
    auto r = __builtin_amdgcn_permlane32_swap(__float_as_int(p), __float_as_int(p),
                                              false, false);
    return __int_as_float(r[0]) + __int_as_float(r[1]);
#else
    return p + __shfl_xor(p, 32);
#endif
}

// Device-scope grid barrier. Correct only if ALL GRID blocks are co-resident:
// __launch_bounds__(256,4) -> VGPR<=128 -> >=4 blocks/CU; LDS 20.4KB -> 7/CU;
// GRID = 4*256 CUs. Release: per-thread __threadfence() (agent fence: L2 wb)
// before arrival; acquire: flag load + trailing fence (L1/L2 inv).
__device__ __forceinline__ void gsync(int* bar, int gen) {
    __threadfence();
    __syncthreads();
    if (threadIdx.x == 0) {
        int v = __hip_atomic_fetch_add(&bar[0], 1, __ATOMIC_ACQ_REL,
                                       __HIP_MEMORY_SCOPE_AGENT);
        if (v == GRID - 1) {
            __hip_atomic_store(&bar[0], 0, __ATOMIC_RELAXED,
                               __HIP_MEMORY_SCOPE_AGENT);
            __hip_atomic_store(&bar[1], gen, __ATOMIC_RELEASE,
                               __HIP_MEMORY_SCOPE_AGENT);
        } else {
            while (__hip_atomic_load(&bar[1], __ATOMIC_ACQUIRE,
                                     __HIP_MEMORY_SCOPE_AGENT) < gen)
                __builtin_amdgcn_s_sleep(2);
        }
    }
    __syncthreads();
    __threadfence();
}

// ---------------------------------------------------------------------------
// One persistent kernel: CVT -> (P0 R0 P1 R1 P2 R2) with 6 grid syncs.
// Block g = (it = g&127, bg = g>>7): i-tile 16 x b-tile 16, 4 waves <-> 4 j.
// Pass phases are verbatim round-5 logic (proven). Reduce phase: block g
// handles (b = g>>3, jd-chunk = (g&7)*32); squash + vacc update inline.
// ---------------------------------------------------------------------------
__global__ __launch_bounds__(256, 4) void caps_mega(
    const float* __restrict__ W,    // [J][I][D][F] f32
    const float* __restrict__ x,    // [B][I][F] f32
    f16* __restrict__ Wt,           // [J][I][D][F] f16
    f16* __restrict__ xt,           // [B][I][F] f16
    f16* __restrict__ sp,           // [NIT][B][JD] f16 partials
    float* __restrict__ vacc,       // [B][JD] f32 running v-sum
    float* __restrict__ out,        // [B][JD] f32
    int* __restrict__ bar)
{
    const int g = blockIdx.x;
    const int it = g & (NIT - 1), bg = g >> 7;
    const int i0 = it * IT, b0 = bg * BT;
    const int t = threadIdx.x;
    const int w = t >> 6, l = t & 63;
    const int lb = l & 15, lq = l >> 4;

    __shared__ f16 xlds[IT][BT][F_];               // 4 KB, persists all passes
    __shared__ union {
        float cl[J_ * IT * BT];                    // softmax coeffs
        float slds[BT * SROW];                     // epilogue transpose
        float red[8][32];                          // reduce partials
    } sh;                                          // 16.4 KB

    // ---- CVT: 262144 threads x (4 W + 2 x) float4s, exact cover ----
    {
        const int tid = g * 256 + t;
        #pragma unroll
        for (int e = 0; e < 4; ++e) {
            const size_t k = (size_t)e * (GRID * 256) + tid;
            float4 a = reinterpret_cast<const float4*>(W)[k];
            f16x4 h = {(f16)a.x, (f16)a.y, (f16)a.z, (f16)a.w};
            reinterpret_cast<f16x4*>(Wt)[k] = h;
        }
        #pragma unroll
        for (int e = 0; e < 2; ++e) {
            const size_t k = (size_t)e * (GRID * 256) + tid;
            float4 a = reinterpret_cast<const float4*>(x)[k];
            f16x4 h = {(f16)a.x, (f16)a.y, (f16)a.z, (f16)a.w};
            reinterpret_cast<f16x4*>(xt)[k] = h;
        }
    }
    gsync(bar, 1);

    // ---- stage x~ tile once (reused by all 3 passes) ----
    {
        const int b = t >> 4, i = t & 15;
        f16x8 v = *reinterpret_cast<const f16x8*>(
            xt + ((size_t)(b0 + b) * I_ + i0 + i) * F_);
        *reinterpret_cast<f16x8*>(&xlds[i][b][0]) = v;
    }
    __syncthreads();

    const f16* wbase = Wt + (((size_t)(w * 4) * I_ + i0) * D_ + lb) * F_;
    const f32x4 zero = {0.f, 0.f, 0.f, 0.f};

    for (int r = 0; r < 3; ++r) {
        // ---- Phase A + softmax (r >= 1) ----
        if (r > 0) {
            float4 vr[4];
            #pragma unroll
            for (int jj = 0; jj < 4; ++jj)
                vr[jj] = *reinterpret_cast<const float4*>(
                    vacc + (size_t)(b0 + lb) * JD + (w * 4 + jj) * D_ + lq * 4);

            #pragma unroll 4
            for (int il = 0; il < IT; ++il) {
                f16x8 bf = {0, 0, 0, 0, 0, 0, 0, 0};
                if (l < 16) bf = *reinterpret_cast<const f16x8*>(&xlds[il][lb][0]);
                #pragma unroll
                for (int jj = 0; jj < 4; ++jj) {
                    f16x8 af = *reinterpret_cast<const f16x8*>(
                        wbase + jj * JSTR + il * (D_ * F_));
                    f32x4 u = __builtin_amdgcn_mfma_f32_16x16x32_f16(
                        af, bf, zero, 0, 0, 0);
                    float p = u[0] * vr[jj].x + u[1] * vr[jj].y +
                              u[2] * vr[jj].z + u[3] * vr[jj].w;
                    p = fold32(fold16(p));
                    if (l < 16) sh.cl[(((w * 4 + jj) * IT) + il) * BT + lb] = p;
                }
            }
            __syncthreads();

            {   // softmax over j: thread (i = t>>4, b = t&15)
                const int i = t >> 4, b = t & 15;
                float e[J_];
                float mx = -1e30f;
                #pragma unroll
                for (int j = 0; j < J_; ++j) {
                    e[j] = sh.cl[(j * IT + i) * BT + b];
                    mx = fmaxf(mx, e[j]);
                }
                float ssum = 0.f;
                #pragma unroll
                for (int j = 0; j < J_; ++j) { e[j] = __expf(e[j] - mx); ssum += e[j]; }
                const float inv = 1.f / ssum;
                #pragma unroll
                for (int j = 0; j < J_; ++j) sh.cl[(j * IT + i) * BT + b] = e[j] * inv;
            }
            __syncthreads();
        }

        // ---- Phase C: s-GEMM, K=(i16,f8)=128 -> 4 MFMAs per j ----
        f32x4 sacc[4] = {zero, zero, zero, zero};
        #pragma unroll
        for (int m = 0; m < 4; ++m) {
            const int i = m * 4 + lq;
            f16x8 xf = *reinterpret_cast<const f16x8*>(&xlds[i][lb][0]);
            #pragma unroll
            for (int jj = 0; jj < 4; ++jj) {
                f16x8 bf;
                if (r > 0) {
                    const f16 ch = (f16)sh.cl[(((w * 4 + jj) * IT) + i) * BT + lb];
                    bf = xf * ch;
                } else {
                    bf = xf;
                }
                f16x8 af = *reinterpret_cast<const f16x8*>(
                    wbase + jj * JSTR + i * (D_ * F_));
                sacc[jj] = __builtin_amdgcn_mfma_f32_16x16x32_f16(
                    af, bf, sacc[jj], 0, 0, 0);
            }
        }
        __syncthreads();   // slds aliases cl: phase-C cl reads must finish

        // ---- epilogue: LDS transpose -> coalesced f16 sp store ----
        #pragma unroll
        for (int jj = 0; jj < 4; ++jj) {
            f32x4 sv = sacc[jj];
            if (r == 0) sv *= 0.0625f;
            const int j = w * 4 + jj;
            #pragma unroll
            for (int rr = 0; rr < 4; ++rr)
                sh.slds[lb * SROW + j * D_ + lq * 4 + rr] = sv[rr];
        }
        __syncthreads();
        {
            const int b = t >> 4, seg = t & 15;
            float o[16];
            #pragma unroll
            for (int k = 0; k < 16; ++k)
                o[k] = sh.slds[b * SROW + seg * 16 + k];
            f16x8 o0 = {(f16)o[0], (f16)o[1], (f16)o[2],  (f16)o[3],
                        (f16)o[4], (f16)o[5], (f16)o[6],  (f16)o[7]};
            f16x8 o1 = {(f16)o[8], (f16)o[9], (f16)o[10], (f16)o[11],
                        (f16)o[12], (f16)o[13], (f16)o[14], (f16)o[15]};
            f16* dst = sp + ((size_t)it * B_ + b0 + b) * JD + seg * 16;
            *reinterpret_cast<f16x8*>(dst) = o0;
            *reinterpret_cast<f16x8*>(dst + 8) = o1;
        }
        gsync(bar, 2 + 2 * r);

        // ---- reduce + squash: block g -> (b = g>>3, jd chunk (g&7)*32) ----
        {
            const int rb = g >> 3, seg = g & 7;
            const int jdo = t & 31, chunk = t >> 5;
            float acc = 0.f;
            const f16* pp = sp + ((size_t)(chunk * 16) * B_ + rb) * JD +
                            seg * 32 + jdo;
            #pragma unroll
            for (int k = 0; k < 16; ++k)
                acc += (float)pp[(size_t)k * B_ * JD];
            sh.red[chunk][jdo] = acc;
            __syncthreads();
            if (t < 32) {
                float s = 0.f;
                #pragma unroll
                for (int c = 0; c < 8; ++c) s += sh.red[c][t];
                const float sq = row_sum16(s * s);
                const float scale = sq / (1.f + sq) * rsqrtf(sq + 1e-7f);
                const float v = scale * s;
                const size_t idx = (size_t)rb * JD + seg * 32 + t;
                if (r == 0)      vacc[idx] = v;
                else if (r == 1) vacc[idx] += v;
                else             out[idx] = v;
            }
        }
        if (r < 2) gsync(bar, 3 + 2 * r);
    }
}

extern "C" void kernel_launch(void* const* d_in, const int* in_sizes, int n_in,
                              void* d_out, int out_size, void* d_ws,
                              size_t ws_size, hipStream_t stream) {
    const float* x = (const float*)d_in[0];   // [128, 2048, 8]
    const float* W = (const float*)d_in[1];   // [16, 2048, 16, 8]
    float* out = (float*)d_out;               // [128, 16, 16]

    const size_t NW = (size_t)J_ * I_ * D_ * F_;   // 4,194,304
    const size_t NX = (size_t)B_ * I_ * F_;        // 2,097,152
    const size_t NSP = (size_t)NIT * B_ * JD;      // 4,194,304

    f16* Wt = (f16*)d_ws;
    f16* xt = Wt + NW;
    f16* sp = xt + NX;
    float* vacc = (float*)(sp + NSP);
    int* bar = (int*)(vacc + (size_t)B_ * JD);

    // barrier state must be zero at kernel start on every replay
    hipMemsetAsync(bar, 0, 64, stream);

    caps_mega<<<GRID, 256, 0, stream>>>(W, x, Wt, xt, sp, vacc, out, bar);
}

// Round 9
// 123.628 us; speedup vs baseline: 12.6364x; 12.6364x over previous
//
#include <hip/hip_runtime.h>
#include <math.h>

// Problem constants
#define B_   128
#define I_   2048
#define F_   8
#define J_   16
#define D_   16
#define JD   256
#define IT   16
#define NIT  (I_/IT)       // 128
#define BT   32            // b per block (4x less W duplication than BT=16)
#define NBG  (B_/BT)       // 4
#define SROW 257           // padded slds row stride (f32)
#define CLS  33            // padded cl b-stride (f32) -> conflict-free phase-C reads
#define JSTR ((size_t)I_*D_*F_)

typedef _Float16 f16;
typedef _Float16 f16x8 __attribute__((ext_vector_type(8)));
typedef float    f32x4 __attribute__((ext_vector_type(4)));

#if defined(__has_builtin)
#  if __has_builtin(__builtin_amdgcn_permlane32_swap)
#    define HAVE_PLS32 1
#  endif
#endif

// 16-lane DPP sum — pure VALU (reduce kernel)
template <int CTRL>
__device__ __forceinline__ float dpp_add(float v) {
    int t = __builtin_amdgcn_update_dpp(0, __float_as_int(v), CTRL, 0xF, 0xF, true);
    return v + __int_as_float(t);
}
__device__ __forceinline__ float row_sum16(float v) {
    v = dpp_add<0x128>(v);
    v = dpp_add<0x124>(v);
    v = dpp_add<0x122>(v);
    v = dpp_add<0x121>(v);
    return v;
}

// quarter-sum folds for MFMA C-layout (proven rounds 5-7)
__device__ __forceinline__ float fold16(float p) {
    return p + __int_as_float(__builtin_amdgcn_ds_swizzle(__float_as_int(p), 0x401F));
}
__device__ __forceinline__ float fold32(float p) {
#ifdef HAVE_PLS32
    auto r = __builtin_amdgcn_permlane32_swap(__float_as_int(p), __float_as_int(p),
                                              false, false);
    return __int_as_float(r[0]) + __int_as_float(r[1]);
#else
    return p + __shfl_xor(p, 32);
#endif
}

__device__ __forceinline__ f16x8 cvt8(float4 a0, float4 a1) {
    f16x8 h = {(f16)a0.x, (f16)a0.y, (f16)a0.z, (f16)a0.w,
               (f16)a1.x, (f16)a1.y, (f16)a1.z, (f16)a1.w};
    return h;
}

// ---------------------------------------------------------------------------
// Pass kernel. Grid (NIT=128, NBG=4), 256 threads = 4 waves <-> 4 j each.
// Lane: lb = l&15 (b-col or d-row), lq = l>>4.
// PASS==0 (fused cvt): reads W/x in f32, converts in-register; bg==0 writes
//   Wt, every block writes its unique xt tile; phase C only (c = 1/16).
// PASS==1: phase A streams Wt ONCE, capturing the phase-C A-fragments into
//   registers afc[4][4] when (il&3)==lq; logits via 4-FMA + fold16/fold32;
//   per-thread softmax; phase C reuses afc (no second W stream).
// Epilogue: LDS transpose -> coalesced f16 store to sp[it][b][jd].
// ---------------------------------------------------------------------------
template <int PASS>
__global__ __launch_bounds__(256) void caps_pass(
    const float* __restrict__ Wf,   // [J][I][D][F] f32 (PASS==0)
    const float* __restrict__ xf,   // [B][I][F] f32   (PASS==0)
    f16* __restrict__ Wt,           // [J][I][D][F] f16 (written P0, read P1)
    f16* __restrict__ xt,           // [B][I][F] f16
    const float* __restrict__ vsum, // [B][JD] (PASS==1)
    f16* __restrict__ sp)           // [NIT][B][JD] f16
{
    const int it = blockIdx.x, bg = blockIdx.y;
    const int i0 = it * IT, b0 = bg * BT;
    const int t = threadIdx.x;
    const int w = t >> 6, l = t & 63;
    const int lb = l & 15, lq = l >> 4;

    __shared__ f16 xlds[IT][BT][F_];                       // 8 KB
    __shared__ union {
        float cl[J_ * IT * CLS];                           // 33.8 KB
        float slds[BT * SROW];                             // 32.9 KB
    } sh;

    // ---- stage x tile: thread (b = t>>3, ii = (t&7)*2) does 2 i's ----
    {
        const int b = t >> 3, ii = (t & 7) * 2;
        #pragma unroll
        for (int k = 0; k < 2; ++k) {
            const size_t off = ((size_t)(b0 + b) * I_ + i0 + ii + k) * F_;
            f16x8 h;
            if constexpr (PASS == 0) {
                const float4* src = reinterpret_cast<const float4*>(xf + off);
                h = cvt8(src[0], src[1]);
                *reinterpret_cast<f16x8*>(xt + off) = h;   // unique tile
            } else {
                h = *reinterpret_cast<const f16x8*>(xt + off);
            }
            *reinterpret_cast<f16x8*>(&xlds[ii + k][b][0]) = h;
        }
    }

    f16x8 afc[4][4];    // phase-C A-fragments: afc[m][jj], i = m*4+lq, d = lb

    if constexpr (PASS == 0) {
        // load + convert this block's W-tile directly in phase-C layout
        #pragma unroll
        for (int m = 0; m < 4; ++m)
            #pragma unroll
            for (int jj = 0; jj < 4; ++jj) {
                const size_t off =
                    (((size_t)(w * 4 + jj) * I_ + i0 + m * 4 + lq) * D_ + lb) * F_;
                const float4* src = reinterpret_cast<const float4*>(Wf + off);
                f16x8 h = cvt8(src[0], src[1]);
                afc[m][jj] = h;
                if (bg == 0) *reinterpret_cast<f16x8*>(Wt + off) = h;
            }
    }
    __syncthreads();

    const f32x4 zero = {0.f, 0.f, 0.f, 0.f};

    if constexpr (PASS == 1) {
        // v fragments: vrh[bh][jj] = vsum[b0+bh*16+lb][j][lq*4 .. +3]
        float4 vrh[2][4];
        #pragma unroll
        for (int bh = 0; bh < 2; ++bh)
            #pragma unroll
            for (int jj = 0; jj < 4; ++jj)
                vrh[bh][jj] = *reinterpret_cast<const float4*>(
                    vsum + (size_t)(b0 + bh * 16 + lb) * JD +
                    (w * 4 + jj) * D_ + lq * 4);

        const f16* wp[4];
        #pragma unroll
        for (int jj = 0; jj < 4; ++jj)
            wp[jj] = Wt + (((size_t)(w * 4 + jj) * I_ + i0) * D_ + lb) * F_;

        // ---- Phase A: logits; capture afc when (il&3)==lq ----
        #pragma unroll
        for (int il = 0; il < IT; ++il) {
            f16x8 bf0 = {0, 0, 0, 0, 0, 0, 0, 0};
            f16x8 bf1 = {0, 0, 0, 0, 0, 0, 0, 0};
            if (l < 16) {
                bf0 = *reinterpret_cast<const f16x8*>(&xlds[il][lb][0]);
                bf1 = *reinterpret_cast<const f16x8*>(&xlds[il][16 + lb][0]);
            }
            #pragma unroll
            for (int jj = 0; jj < 4; ++jj) {
                f16x8 af = *reinterpret_cast<const f16x8*>(wp[jj] + il * (D_ * F_));
                if ((il & 3) == lq) afc[il >> 2][jj] = af;
                f32x4 u0 = __builtin_amdgcn_mfma_f32_16x16x32_f16(af, bf0, zero, 0, 0, 0);
                float p0 = u0[0] * vrh[0][jj].x + u0[1] * vrh[0][jj].y +
                           u0[2] * vrh[0][jj].z + u0[3] * vrh[0][jj].w;
                p0 = fold32(fold16(p0));
                f32x4 u1 = __builtin_amdgcn_mfma_f32_16x16x32_f16(af, bf1, zero, 0, 0, 0);
                float p1 = u1[0] * vrh[1][jj].x + u1[1] * vrh[1][jj].y +
                           u1[2] * vrh[1][jj].z + u1[3] * vrh[1][jj].w;
                p1 = fold32(fold16(p1));
                if (l < 16) {
                    sh.cl[((w * 4 + jj) * IT + il) * CLS + lb] = p0;
                    sh.cl[((w * 4 + jj) * IT + il) * CLS + 16 + lb] = p1;
                }
            }
        }
        __syncthreads();

        // ---- softmax over j: 512 (i,b) items, 2 per thread ----
        #pragma unroll
        for (int hh = 0; hh < 2; ++hh) {
            const int item = hh * 256 + t;
            const int i = item >> 5, b = item & 31;
            float e[J_];
            float mx = -1e30f;
            #pragma unroll
            for (int j = 0; j < J_; ++j) {
                e[j] = sh.cl[(j * IT + i) * CLS + b];
                mx = fmaxf(mx, e[j]);
            }
            float ssum = 0.f;
            #pragma unroll
            for (int j = 0; j < J_; ++j) { e[j] = __expf(e[j] - mx); ssum += e[j]; }
            const float inv = 1.f / ssum;
            #pragma unroll
            for (int j = 0; j < J_; ++j) sh.cl[(j * IT + i) * CLS + b] = e[j] * inv;
        }
        __syncthreads();
    }

    // ---- Phase C: s-GEMM from register A-fragments, K=(i16,f8)=128 ----
    f32x4 sacc[4][2];
    #pragma unroll
    for (int jj = 0; jj < 4; ++jj) { sacc[jj][0] = zero; sacc[jj][1] = zero; }

    #pragma unroll
    for (int m = 0; m < 4; ++m) {
        const int i = m * 4 + lq;
        f16x8 xf0 = *reinterpret_cast<const f16x8*>(&xlds[i][lb][0]);
        f16x8 xf1 = *reinterpret_cast<const f16x8*>(&xlds[i][16 + lb][0]);
        #pragma unroll
        for (int jj = 0; jj < 4; ++jj) {
            f16x8 b0v, b1v;
            if constexpr (PASS == 1) {
                const f16 c0 = (f16)sh.cl[((w * 4 + jj) * IT + i) * CLS + lb];
                const f16 c1 = (f16)sh.cl[((w * 4 + jj) * IT + i) * CLS + 16 + lb];
                b0v = xf0 * c0;
                b1v = xf1 * c1;
            } else {
                b0v = xf0;
                b1v = xf1;
            }
            sacc[jj][0] = __builtin_amdgcn_mfma_f32_16x16x32_f16(
                afc[m][jj], b0v, sacc[jj][0], 0, 0, 0);
            sacc[jj][1] = __builtin_amdgcn_mfma_f32_16x16x32_f16(
                afc[m][jj], b1v, sacc[jj][1], 0, 0, 0);
        }
    }
    __syncthreads();   // slds aliases cl: phase-C cl reads must finish

    // ---- epilogue: LDS transpose -> coalesced f16 sp store ----
    #pragma unroll
    for (int jj = 0; jj < 4; ++jj) {
        #pragma unroll
        for (int bh = 0; bh < 2; ++bh) {
            f32x4 sv = sacc[jj][bh];
            if constexpr (PASS == 0) sv *= 0.0625f;
            const int j = w * 4 + jj;
            #pragma unroll
            for (int r = 0; r < 4; ++r)
                sh.slds[(bh * 16 + lb) * SROW + j * D_ + lq * 4 + r] = sv[r];
        }
    }
    __syncthreads();
    {
        const int b = t >> 3, seg = t & 7;   // 32 b x 8 segments of 32 jd
        float o[32];
        #pragma unroll
        for (int k = 0; k < 32; ++k)
            o[k] = sh.slds[b * SROW + seg * 32 + k];
        f16* dst = sp + ((size_t)it * B_ + b0 + b) * JD + seg * 32;
        #pragma unroll
        for (int q = 0; q < 4; ++q) {
            f16x8 h = {(f16)o[q * 8 + 0], (f16)o[q * 8 + 1], (f16)o[q * 8 + 2],
                       (f16)o[q * 8 + 3], (f16)o[q * 8 + 4], (f16)o[q * 8 + 5],
                       (f16)o[q * 8 + 6], (f16)o[q * 8 + 7]};
            *reinterpret_cast<f16x8*>(dst + q * 8) = h;
        }
    }
}

// ---------------------------------------------------------------------------
// Reduce over i-tiles + squash (proven round 7). Grid (B, 2 jd-halves), 512.
// MODE 0: vA = squash(s); MODE 1: vB = vA + squash(s); MODE 2: out = squash(s)
// ---------------------------------------------------------------------------
template <int NITT, int MODE>
__global__ __launch_bounds__(512) void caps_reduce(
    const f16* __restrict__ sp,    // [NITT][B][JD] f16
    const float* __restrict__ vA,  // [B][JD] (MODE==1)
    float* __restrict__ vout)      // [B][JD]
{
    const int b = blockIdx.x, jh = blockIdx.y;
    const int t = threadIdx.x;
    const int g = t >> 4, c8 = t & 15;
    constexpr int ITS = NITT / 32;

    float acc[8] = {0.f, 0.f, 0.f, 0.f, 0.f, 0.f, 0.f, 0.f};
    const f16* base = sp + ((size_t)(g * ITS) * B_ + b) * JD + jh * 128 + c8 * 8;
    #pragma unroll
    for (int k = 0; k < ITS; ++k) {
        f16x8 v = *reinterpret_cast<const f16x8*>(base + (size_t)k * B_ * JD);
        #pragma unroll
        for (int e = 0; e < 8; ++e) acc[e] += (float)v[e];
    }

    __shared__ float lds[32][128];
    #pragma unroll
    for (int e = 0; e < 8; ++e) lds[g][c8 * 8 + e] = acc[e];
    __syncthreads();

    if (t < 128) {
        float a = 0.f;
        #pragma unroll
        for (int gg = 0; gg < 32; ++gg) a += lds[gg][t];
        const float sq = row_sum16(a * a);
        const float scale = sq / (1.f + sq) * rsqrtf(sq + 1e-7f);
        float v = scale * a;
        const int jd = jh * 128 + t;
        if (MODE == 1) v += vA[(size_t)b * JD + jd];
        vout[(size_t)b * JD + jd] = v;
    }
}

extern "C" void kernel_launch(void* const* d_in, const int* in_sizes, int n_in,
                              void* d_out, int out_size, void* d_ws,
                              size_t ws_size, hipStream_t stream) {
    const float* x = (const float*)d_in[0];   // [128, 2048, 8]
    const float* W = (const float*)d_in[1];   // [16, 2048, 16, 8]
    float* out = (float*)d_out;               // [128, 16, 16]

    const size_t NW = (size_t)J_ * I_ * D_ * F_;   // 4,194,304
    const size_t NX = (size_t)B_ * I_ * F_;        // 2,097,152
    const size_t NSP = (size_t)NIT * B_ * JD;      // 4,194,304

    f16* Wt = (f16*)d_ws;
    f16* xt = Wt + NW;
    f16* sp = xt + NX;
    float* vA = (float*)(sp + NSP);
    float* vB = vA + (size_t)B_ * JD;

    dim3 grid(NIT, NBG), blk(256);
    dim3 rgrid(B_, 2), rblk(512);

    // r=0 (+ fused f32->f16 cvt): uniform c -> sp -> vA = v0
    caps_pass<0><<<grid, blk, 0, stream>>>(W, x, Wt, xt, nullptr, sp);
    caps_reduce<NIT, 0><<<rgrid, rblk, 0, stream>>>(sp, nullptr, vA);
    // r=1: logits = v0.u_hat -> sp -> vB = v0 + v1
    caps_pass<1><<<grid, blk, 0, stream>>>(nullptr, nullptr, Wt, xt, vA, sp);
    caps_reduce<NIT, 1><<<rgrid, rblk, 0, stream>>>(sp, vA, vB);
    // r=2: logits = (v0+v1).u_hat -> sp -> out
    caps_pass<1><<<grid, blk, 0, stream>>>(nullptr, nullptr, Wt, xt, vB, sp);
    caps_reduce<NIT, 2><<<rgrid, rblk, 0, stream>>>(sp, nullptr, out);
}

// Round 10
// 82.332 us; speedup vs baseline: 18.9747x; 1.5016x over previous
//
#include <hip/hip_runtime.h>
#include <math.h>

// Problem constants
#define B_   128
#define I_   2048
#define F_   8
#define J_   16
#define D_   16
#define JD   256
#define IT   16
#define NIT  (I_/IT)       // 128
#define BT   16
#define NBG  (B_/BT)       // 8
#define SROW 257           // padded slds row stride (f32)

typedef _Float16 f16;
typedef _Float16 f16x8 __attribute__((ext_vector_type(8)));
typedef float    f32x4 __attribute__((ext_vector_type(4)));

#if defined(__has_builtin)
#  if __has_builtin(__builtin_amdgcn_permlane32_swap)
#    define HAVE_PLS32 1
#  endif
#endif

// 16-lane DPP sum — pure VALU
template <int CTRL>
__device__ __forceinline__ float dpp_add(float v) {
    int t = __builtin_amdgcn_update_dpp(0, __float_as_int(v), CTRL, 0xF, 0xF, true);
    return v + __int_as_float(t);
}
__device__ __forceinline__ float row_sum16(float v) {
    v = dpp_add<0x128>(v);
    v = dpp_add<0x124>(v);
    v = dpp_add<0x122>(v);
    v = dpp_add<0x121>(v);
    return v;
}

// quarter-sum folds for MFMA C-layout (proven rounds 5-7)
__device__ __forceinline__ float fold16(float p) {
    return p + __int_as_float(__builtin_amdgcn_ds_swizzle(__float_as_int(p), 0x401F));
}
__device__ __forceinline__ float fold32(float p) {
#ifdef HAVE_PLS32
    auto r = __builtin_amdgcn_permlane32_swap(__float_as_int(p), __float_as_int(p),
                                              false, false);
    return __int_as_float(r[0]) + __int_as_float(r[1]);
#else
    return p + __shfl_xor(p, 32);
#endif
}

__device__ __forceinline__ f16x8 cvt8(float4 a0, float4 a1) {
    f16x8 h = {(f16)a0.x, (f16)a0.y, (f16)a0.z, (f16)a0.w,
               (f16)a1.x, (f16)a1.y, (f16)a1.z, (f16)a1.w};
    return h;
}

// ---------------------------------------------------------------------------
// Pass 0 with fused f32->f16 conversion. Grid (NIT, NBG), 256 thr = 4 waves.
// Reads W/x in f32 (coalesced), converts in-register (only 1 fragment live
// per jj iteration -> no VGPR blowup), writes Wt (bg==0 only) and the
// block-unique xt tile, computes s0 with c = 1/16 (scale folded at end).
// Epilogue identical to the proven round-5 kernel.
// ---------------------------------------------------------------------------
__global__ __launch_bounds__(256) void caps_pass0(
    const float* __restrict__ Wf,   // [J][I][D][F] f32
    const float* __restrict__ xf,   // [B][I][F] f32
    f16* __restrict__ Wt,           // [J][I][D][F] f16 (out)
    f16* __restrict__ xt,           // [B][I][F] f16 (out)
    f16* __restrict__ sp)           // [NIT][B][JD] f16
{
    const int it = blockIdx.x, bg = blockIdx.y;
    const int i0 = it * IT, b0 = bg * BT;
    const int t = threadIdx.x;
    const int w = t >> 6, l = t & 63;
    const int lb = l & 15, lq = l >> 4;

    __shared__ f16   xlds[IT][BT][F_];   // 4 KB
    __shared__ float slds[BT * SROW];    // 16.4 KB

    // stage + convert x tile; write the block-unique xt tile
    {
        const int b = t >> 4, i = t & 15;
        const size_t off = ((size_t)(b0 + b) * I_ + i0 + i) * F_;
        const float4* src = reinterpret_cast<const float4*>(xf + off);
        f16x8 h = cvt8(src[0], src[1]);
        *reinterpret_cast<f16x8*>(xt + off) = h;
        *reinterpret_cast<f16x8*>(&xlds[i][b][0]) = h;
    }
    __syncthreads();

    const f32x4 zero = {0.f, 0.f, 0.f, 0.f};
    f32x4 sacc[4] = {zero, zero, zero, zero};

    // Phase C: s-GEMM with in-flight conversion. K=(i16,f8)=128.
    #pragma unroll
    for (int m = 0; m < 4; ++m) {
        const int i = m * 4 + lq;
        f16x8 xv = *reinterpret_cast<const f16x8*>(&xlds[i][lb][0]);
        #pragma unroll
        for (int jj = 0; jj < 4; ++jj) {
            const size_t off =
                (((size_t)(w * 4 + jj) * I_ + i0 + i) * D_ + lb) * F_;
            const float4* sw = reinterpret_cast<const float4*>(Wf + off);
            f16x8 af = cvt8(sw[0], sw[1]);
            if (bg == 0) *reinterpret_cast<f16x8*>(Wt + off) = af;
            sacc[jj] = __builtin_amdgcn_mfma_f32_16x16x32_f16(
                af, xv, sacc[jj], 0, 0, 0);
        }
    }

    // epilogue: scale 1/16, LDS transpose, coalesced f16 store
    #pragma unroll
    for (int jj = 0; jj < 4; ++jj) {
        f32x4 sv = sacc[jj] * 0.0625f;
        const int j = w * 4 + jj;
        #pragma unroll
        for (int r = 0; r < 4; ++r)
            slds[lb * SROW + j * D_ + lq * 4 + r] = sv[r];
    }
    __syncthreads();
    {
        const int b = t >> 4, seg = t & 15;
        float o[16];
        #pragma unroll
        for (int k = 0; k < 16; ++k)
            o[k] = slds[b * SROW + seg * 16 + k];
        f16x8 o0 = {(f16)o[0], (f16)o[1], (f16)o[2],  (f16)o[3],
                    (f16)o[4], (f16)o[5], (f16)o[6],  (f16)o[7]};
        f16x8 o1 = {(f16)o[8], (f16)o[9], (f16)o[10], (f16)o[11],
                    (f16)o[12], (f16)o[13], (f16)o[14], (f16)o[15]};
        f16* dst = sp + ((size_t)it * B_ + b0 + b) * JD + seg * 16;
        *reinterpret_cast<f16x8*>(dst) = o0;
        *reinterpret_cast<f16x8*>(dst + 8) = o1;
    }
}

// ---------------------------------------------------------------------------
// Pass 1/2 — VERBATIM round-5 kernel (proven: 80 us pipeline, VGPR ~56).
// Block = (i-tile 16) x (b-tile 16), 4 waves <-> 4 j each.
// Phase A: per (j,il): u[d,b] = mfma(W~,x~) (K=8 of 32); logit via 4 FMA +
// fold16/fold32; lanes<16 write cl. Softmax per (b,i) thread. Phase C:
// s-GEMM K=128, B-frag c*x~ in-register. Epilogue: LDS transpose -> sp.
// ---------------------------------------------------------------------------
__global__ __launch_bounds__(256) void caps_pass1(
    const f16* __restrict__ Wt,     // [J][I][D][F]
    const f16* __restrict__ xt,     // [B][I][F]
    const float* __restrict__ vsum, // [B][JD]
    f16* __restrict__ sp)           // [NIT][B][JD]
{
    const int it = blockIdx.x, bg = blockIdx.y;
    const int i0 = it * IT, b0 = bg * BT;
    const int t = threadIdx.x;
    const int w = t >> 6, l = t & 63;
    const int lb = l & 15, lq = l >> 4;

    __shared__ f16 xlds[IT][BT][F_];        // 4 KB
    __shared__ union {
        float cl[J_ * IT * BT];             // 16 KB softmax coeffs
        float slds[BT * SROW];              // 16.4 KB epilogue transpose
    } sh;

    // stage x~ tile
    {
        const int b = t >> 4, i = t & 15;
        f16x8 v = *reinterpret_cast<const f16x8*>(
            xt + ((size_t)(b0 + b) * I_ + i0 + i) * F_);
        *reinterpret_cast<f16x8*>(&xlds[i][b][0]) = v;
    }

    // per-j W~ base pointers (row d = lb, f contiguous)
    const f16* wp[4];
    #pragma unroll
    for (int jj = 0; jj < 4; ++jj)
        wp[jj] = Wt + (((size_t)(w * 4 + jj) * I_ + i0) * D_ + lb) * F_;

    const f32x4 zero = {0.f, 0.f, 0.f, 0.f};
    f32x4 sacc[4] = {zero, zero, zero, zero};

    // v fragments: vr[jj] = vsum[b0+lb][j][lq*4 .. +3]
    float4 vr[4];
    #pragma unroll
    for (int jj = 0; jj < 4; ++jj)
        vr[jj] = *reinterpret_cast<const float4*>(
            vsum + (size_t)(b0 + lb) * JD + (w * 4 + jj) * D_ + lq * 4);
    __syncthreads();

    // ---- Phase A: logits ----
    #pragma unroll 4
    for (int il = 0; il < IT; ++il) {
        f16x8 bf = {0, 0, 0, 0, 0, 0, 0, 0};
        if (l < 16) bf = *reinterpret_cast<const f16x8*>(&xlds[il][lb][0]);
        #pragma unroll
        for (int jj = 0; jj < 4; ++jj) {
            f16x8 af = *reinterpret_cast<const f16x8*>(wp[jj] + il * (D_ * F_));
            f32x4 u = __builtin_amdgcn_mfma_f32_16x16x32_f16(af, bf, zero, 0, 0, 0);
            float p = u[0] * vr[jj].x + u[1] * vr[jj].y +
                      u[2] * vr[jj].z + u[3] * vr[jj].w;
            p = fold32(fold16(p));
            if (l < 16) sh.cl[(((w * 4 + jj) * IT) + il) * BT + lb] = p;
        }
    }
    __syncthreads();

    // ---- softmax over j: thread (i = t>>4, b = t&15) ----
    {
        const int i = t >> 4, b = t & 15;
        float e[J_];
        float mx = -1e30f;
        #pragma unroll
        for (int j = 0; j < J_; ++j) {
            e[j] = sh.cl[(j * IT + i) * BT + b];
            mx = fmaxf(mx, e[j]);
        }
        float ssum = 0.f;
        #pragma unroll
        for (int j = 0; j < J_; ++j) { e[j] = __expf(e[j] - mx); ssum += e[j]; }
        const float inv = 1.f / ssum;
        #pragma unroll
        for (int j = 0; j < J_; ++j) sh.cl[(j * IT + i) * BT + b] = e[j] * inv;
    }
    __syncthreads();

    // ---- Phase C: s-GEMM, K=(i16,f8)=128 -> 4 MFMAs per j ----
    #pragma unroll
    for (int m = 0; m < 4; ++m) {
        const int i = m * 4 + lq;
        f16x8 xv = *reinterpret_cast<const f16x8*>(&xlds[i][lb][0]);
        #pragma unroll
        for (int jj = 0; jj < 4; ++jj) {
            const f16 ch = (f16)sh.cl[(((w * 4 + jj) * IT) + i) * BT + lb];
            f16x8 bf = xv * ch;            // v_pk_mul_f16
            f16x8 af = *reinterpret_cast<const f16x8*>(wp[jj] + i * (D_ * F_));
            sacc[jj] = __builtin_amdgcn_mfma_f32_16x16x32_f16(
                af, bf, sacc[jj], 0, 0, 0);
        }
    }
    __syncthreads();   // slds aliases cl: phase-C cl reads must finish

    // ---- epilogue: LDS transpose -> coalesced f16 store ----
    #pragma unroll
    for (int jj = 0; jj < 4; ++jj) {
        const int j = w * 4 + jj;
        #pragma unroll
        for (int r = 0; r < 4; ++r)
            sh.slds[lb * SROW + j * D_ + lq * 4 + r] = sacc[jj][r];
    }
    __syncthreads();
    {
        const int b = t >> 4, seg = t & 15;
        float o[16];
        #pragma unroll
        for (int k = 0; k < 16; ++k)
            o[k] = sh.slds[b * SROW + seg * 16 + k];
        f16x8 o0 = {(f16)o[0], (f16)o[1], (f16)o[2],  (f16)o[3],
                    (f16)o[4], (f16)o[5], (f16)o[6],  (f16)o[7]};
        f16x8 o1 = {(f16)o[8], (f16)o[9], (f16)o[10], (f16)o[11],
                    (f16)o[12], (f16)o[13], (f16)o[14], (f16)o[15]};
        f16* dst = sp + ((size_t)it * B_ + b0 + b) * JD + seg * 16;
        *reinterpret_cast<f16x8*>(dst) = o0;
        *reinterpret_cast<f16x8*>(dst + 8) = o1;
    }
}

// ---------------------------------------------------------------------------
// Reduce over i-tiles + squash (proven round 7). Grid (B, 2 jd-halves), 512.
// MODE 0: vA = squash(s); MODE 1: vB = vA + squash(s); MODE 2: out = squash(s)
// ---------------------------------------------------------------------------
template <int MODE>
__global__ __launch_bounds__(512) void caps_reduce(
    const f16* __restrict__ sp,    // [NIT][B][JD] f16
    const float* __restrict__ vA,  // [B][JD] (MODE==1)
    float* __restrict__ vout)      // [B][JD]
{
    const int b = blockIdx.x, jh = blockIdx.y;
    const int t = threadIdx.x;
    const int g = t >> 4, c8 = t & 15;
    constexpr int ITS = NIT / 32;  // 4

    float acc[8] = {0.f, 0.f, 0.f, 0.f, 0.f, 0.f, 0.f, 0.f};
    const f16* base = sp + ((size_t)(g * ITS) * B_ + b) * JD + jh * 128 + c8 * 8;
    #pragma unroll
    for (int k = 0; k < ITS; ++k) {
        f16x8 v = *reinterpret_cast<const f16x8*>(base + (size_t)k * B_ * JD);
        #pragma unroll
        for (int e = 0; e < 8; ++e) acc[e] += (float)v[e];
    }

    __shared__ float lds[32][128];
    #pragma unroll
    for (int e = 0; e < 8; ++e) lds[g][c8 * 8 + e] = acc[e];
    __syncthreads();

    if (t < 128) {
        float a = 0.f;
        #pragma unroll
        for (int gg = 0; gg < 32; ++gg) a += lds[gg][t];
        const float sq = row_sum16(a * a);
        const float scale = sq / (1.f + sq) * rsqrtf(sq + 1e-7f);
        float v = scale * a;
        const int jd = jh * 128 + t;
        if (MODE == 1) v += vA[(size_t)b * JD + jd];
        vout[(size_t)b * JD + jd] = v;
    }
}

extern "C" void kernel_launch(void* const* d_in, const int* in_sizes, int n_in,
                              void* d_out, int out_size, void* d_ws,
                              size_t ws_size, hipStream_t stream) {
    const float* x = (const float*)d_in[0];   // [128, 2048, 8]
    const float* W = (const float*)d_in[1];   // [16, 2048, 16, 8]
    float* out = (float*)d_out;               // [128, 16, 16]

    const size_t NW = (size_t)J_ * I_ * D_ * F_;   // 4,194,304
    const size_t NX = (size_t)B_ * I_ * F_;        // 2,097,152
    const size_t NSP = (size_t)NIT * B_ * JD;      // 4,194,304

    f16* Wt = (f16*)d_ws;
    f16* xt = Wt + NW;
    f16* sp = xt + NX;
    float* vA = (float*)(sp + NSP);
    float* vB = vA + (size_t)B_ * JD;

    dim3 grid(NIT, NBG), blk(256);
    dim3 rgrid(B_, 2), rblk(512);

    // r=0 (+ fused cvt): uniform c -> sp -> vA = v0
    caps_pass0<<<grid, blk, 0, stream>>>(W, x, Wt, xt, sp);
    caps_reduce<0><<<rgrid, rblk, 0, stream>>>(sp, nullptr, vA);
    // r=1: logits = v0.u_hat -> sp -> vB = v0 + v1
    caps_pass1<<<grid, blk, 0, stream>>>(Wt, xt, vA, sp);
    caps_reduce<1><<<rgrid, rblk, 0, stream>>>(sp, vA, vB);
    // r=2: logits = (v0+v1).u_hat -> sp -> out
    caps_pass1<<<grid, blk, 0, stream>>>(Wt, xt, vB, sp);
    caps_reduce<2><<<rgrid, rblk, 0, stream>>>(sp, nullptr, out);
}